// Round 2
// baseline (683.916 us; speedup 1.0000x reference)
//
#include <hip/hip_runtime.h>
#include <hip/hip_bf16.h>
#include <stdint.h>
#include <type_traits>

#define Bb 8
#define Tt 2048
#define Cc 512

typedef __attribute__((ext_vector_type(8))) short short8;
typedef __attribute__((ext_vector_type(4))) float f32x4;

__device__ __forceinline__ float b2f(short s) {
  unsigned int x = ((unsigned int)(unsigned short)s) << 16;
  return __builtin_bit_cast(float, x);
}
__device__ __forceinline__ short f2b(float f) {
  unsigned int x = __builtin_bit_cast(unsigned int, f);
  x += 0x7fffu + ((x >> 16) & 1u);   // round-to-nearest-even
  return (short)(x >> 16);
}

// ---------------------------------------------------------------------------
// GEMM: C[m,n] = epilogue( sum_k A[m,k] * B[n,k] )   (B given row-major N x K)
// MODE 0: A fp32, B fp32, C bf16, +bias[n]            (pointwise conv)
// MODE 1: A bf16, B bf16, C bf16, *scale              (scores)
// MODE 2: A bf16, B bf16, C bf16, none                (PV)
// MODE 3: A bf16, B fp32, C fp32, +bias[n]+resid[m,n] (output proj + residual)
// 128x128 tile, BK=64, 4 waves as 2x2, wave tile 64x64 via 4x4 MFMA 16x16x32.
// LDS: 16B chunk (m,kc) at ((kc*128 + (m^kc))*8) -> coalesced global loads AND
// conflict-free b128 LDS reads/writes. M,N mult of 128; K mult of 64.
// ---------------------------------------------------------------------------
template<int MODE>
__global__ __launch_bounds__(256, 2)
void gemm_bt(const void* __restrict__ Av, const void* __restrict__ Bv,
             void* __restrict__ Cv, const float* __restrict__ bias,
             const float* __restrict__ resid,
             int M, int N, int K,
             long long sA, long long sB, long long sC, float scale)
{
  constexpr bool AF32 = (MODE == 0);
  constexpr bool BF32 = (MODE == 0 || MODE == 3);
  constexpr bool CF32 = (MODE == 3);

  __shared__ __align__(16) short ldsA[8 * 128 * 8];
  __shared__ __align__(16) short ldsB[8 * 128 * 8];
  const int tid  = threadIdx.x;
  const int lane = tid & 63;
  const int bm = blockIdx.y * 128;
  const int bn = blockIdx.x * 128;
  const long long zoA = (long long)blockIdx.z * sA;
  const long long zoB = (long long)blockIdx.z * sB;
  const long long zoC = (long long)blockIdx.z * sC;
  const int wv = tid >> 6;
  const int wm = (wv >> 1) << 6;
  const int wn = (wv & 1) << 6;

  f32x4 zero4 = {0.f, 0.f, 0.f, 0.f};
  f32x4 acc[4][4];
#pragma unroll
  for (int i = 0; i < 4; ++i)
#pragma unroll
    for (int j = 0; j < 4; ++j)
      acc[i][j] = zero4;

  const int sm  = tid >> 3;  // 0..31
  const int skc = tid & 7;   // 0..7 k-chunk of 8 elems

  for (int k0 = 0; k0 < K; k0 += 64) {
#pragma unroll
    for (int r = 0; r < 4; ++r) {
      const int m = r * 32 + sm;
      short8 av, bv;
      if constexpr (AF32) {
        const float* ap = (const float*)Av + zoA + (size_t)(bm + m) * K + k0 + skc * 8;
        float4 f0 = *(const float4*)ap;
        float4 f1 = *(const float4*)(ap + 4);
        av[0] = f2b(f0.x); av[1] = f2b(f0.y); av[2] = f2b(f0.z); av[3] = f2b(f0.w);
        av[4] = f2b(f1.x); av[5] = f2b(f1.y); av[6] = f2b(f1.z); av[7] = f2b(f1.w);
      } else {
        av = *(const short8*)((const short*)Av + zoA + (size_t)(bm + m) * K + k0 + skc * 8);
      }
      if constexpr (BF32) {
        const float* bp = (const float*)Bv + zoB + (size_t)(bn + m) * K + k0 + skc * 8;
        float4 f0 = *(const float4*)bp;
        float4 f1 = *(const float4*)(bp + 4);
        bv[0] = f2b(f0.x); bv[1] = f2b(f0.y); bv[2] = f2b(f0.z); bv[3] = f2b(f0.w);
        bv[4] = f2b(f1.x); bv[5] = f2b(f1.y); bv[6] = f2b(f1.z); bv[7] = f2b(f1.w);
      } else {
        bv = *(const short8*)((const short*)Bv + zoB + (size_t)(bn + m) * K + k0 + skc * 8);
      }
      const int di = ((skc << 7) + (m ^ skc)) << 3;
      *(short8*)&ldsA[di] = av;
      *(short8*)&ldsB[di] = bv;
    }
    __syncthreads();
#pragma unroll
    for (int kk = 0; kk < 2; ++kk) {
      const int kcr = (kk << 2) + (lane >> 4);
      short8 af[4], bfv[4];
#pragma unroll
      for (int i = 0; i < 4; ++i) {
        const int ma = wm + i * 16 + (lane & 15);
        const int nb = wn + i * 16 + (lane & 15);
        af[i]  = *(const short8*)&ldsA[((kcr << 7) + (ma ^ kcr)) << 3];
        bfv[i] = *(const short8*)&ldsB[((kcr << 7) + (nb ^ kcr)) << 3];
      }
#pragma unroll
      for (int i = 0; i < 4; ++i)
#pragma unroll
        for (int j = 0; j < 4; ++j)
          acc[i][j] = __builtin_amdgcn_mfma_f32_16x16x32_bf16(af[i], bfv[j], acc[i][j], 0, 0, 0);
    }
    __syncthreads();
  }

  // C/D layout: col = lane&15, row = (lane>>4)*4 + reg  [measured m89/m91]
#pragma unroll
  for (int i = 0; i < 4; ++i) {
    const int row0 = bm + wm + i * 16 + ((lane >> 4) << 2);
#pragma unroll
    for (int j = 0; j < 4; ++j) {
      const int n = bn + wn + j * 16 + (lane & 15);
      float badd = 0.f;
      if (MODE == 0 || MODE == 3) badd = bias[n];
#pragma unroll
      for (int r = 0; r < 4; ++r) {
        float val = acc[i][j][r];
        if (MODE == 1) val *= scale;
        if (MODE == 0) val += badd;
        if constexpr (CF32) {
          val += badd + resid[zoC + (size_t)(row0 + r) * N + n];
          ((float*)Cv)[zoC + (size_t)(row0 + r) * N + n] = val;
        } else {
          ((short*)Cv)[zoC + (size_t)(row0 + r) * N + n] = f2b(val);
        }
      }
    }
  }
}

// ---------------------------------------------------------------------------
// Depthwise conv k=3 pad=1 over T; H bf16 in, bf16 out, fp32 weights.
// ---------------------------------------------------------------------------
__global__ __launch_bounds__(256)
void dw_kernel(const short* __restrict__ H, const float* __restrict__ w2,
               const float* __restrict__ b2, short* __restrict__ out)
{
  const int idx = blockIdx.x * 256 + threadIdx.x;   // over B*T*C/8
  const int c8 = idx & (Cc / 8 - 1);
  const int bt = idx >> 6;
  const int t  = bt & (Tt - 1);
  const int c  = c8 << 3;
  const short* base = H + (size_t)bt * Cc + c;
  short8 zz = {0, 0, 0, 0, 0, 0, 0, 0};
  short8 hm = zz, hp = zz;
  short8 h0 = *(const short8*)base;
  if (t > 0)      hm = *(const short8*)(base - Cc);
  if (t < Tt - 1) hp = *(const short8*)(base + Cc);
  short8 o;
#pragma unroll
  for (int j = 0; j < 8; ++j) {
    const int cj = c + j;
    float val = b2f(hm[j]) * w2[cj * 3 + 0]
              + b2f(h0[j]) * w2[cj * 3 + 1]
              + b2f(hp[j]) * w2[cj * 3 + 2]
              + b2[cj];
    o[j] = f2b(val);
  }
  *(short8*)(out + (size_t)bt * Cc + c) = o;
}

// ---------------------------------------------------------------------------
// Depthwise conv + transpose: outT[b,c,t] (bf16), coalesced reads (lane = c).
// grid (T/32, C/64, B), block 256.
// ---------------------------------------------------------------------------
__global__ __launch_bounds__(256)
void dwt_kernel(const short* __restrict__ H, const float* __restrict__ w2,
                const float* __restrict__ b2, short* __restrict__ outT)
{
  const int b  = blockIdx.z;
  const int c  = blockIdx.y * 64 + (threadIdx.x & 63);
  const int tb = blockIdx.x * 32 + (threadIdx.x >> 6) * 8;
  const short* base = H + (size_t)b * Tt * Cc + c;
  float h[10];
#pragma unroll
  for (int i = 0; i < 10; ++i) {
    const int t = tb - 1 + i;
    h[i] = (t >= 0 && t < Tt) ? b2f(base[(size_t)t * Cc]) : 0.f;
  }
  const float w0 = w2[c * 3 + 0];
  const float w1 = w2[c * 3 + 1];
  const float wp = w2[c * 3 + 2];
  const float bb = b2[c];
  short8 o;
#pragma unroll
  for (int j = 0; j < 8; ++j)
    o[j] = f2b(h[j] * w0 + h[j + 1] * w1 + h[j + 2] * wp + bb);
  *(short8*)(outT + ((size_t)b * Cc + c) * Tt + tb) = o;
}

// ---------------------------------------------------------------------------
// In-place row softmax over rows of length T=2048 (bf16). One block per row.
// ---------------------------------------------------------------------------
__global__ __launch_bounds__(256)
void softmax_kernel(short* __restrict__ S)
{
  __shared__ float red[4];
  const size_t row = blockIdx.x;
  short8* p = (short8*)(S + row * (size_t)Tt) + threadIdx.x;
  short8 v = *p;
  float x[8];
  float mx = -1e30f;
#pragma unroll
  for (int j = 0; j < 8; ++j) { x[j] = b2f(v[j]); mx = fmaxf(mx, x[j]); }
#pragma unroll
  for (int off = 32; off > 0; off >>= 1) mx = fmaxf(mx, __shfl_xor(mx, off, 64));
  const int wvi = threadIdx.x >> 6;
  if ((threadIdx.x & 63) == 0) red[wvi] = mx;
  __syncthreads();
  mx = fmaxf(fmaxf(red[0], red[1]), fmaxf(red[2], red[3]));
  __syncthreads();
  float s = 0.f;
#pragma unroll
  for (int j = 0; j < 8; ++j) { x[j] = __expf(x[j] - mx); s += x[j]; }
#pragma unroll
  for (int off = 32; off > 0; off >>= 1) s += __shfl_xor(s, off, 64);
  if ((threadIdx.x & 63) == 0) red[wvi] = s;
  __syncthreads();
  const float inv = 1.f / (red[0] + red[1] + red[2] + red[3]);
  short8 o;
#pragma unroll
  for (int j = 0; j < 8; ++j) o[j] = f2b(x[j] * inv);
  *p = o;
}

// ---------------------------------------------------------------------------
extern "C" void kernel_launch(void* const* d_in, const int* in_sizes, int n_in,
                              void* d_out, int out_size, void* d_ws, size_t ws_size,
                              hipStream_t stream)
{
  const float* x_l    = (const float*)d_in[0];
  const float* x_r    = (const float*)d_in[1];
  const float* lp1_w1 = (const float*)d_in[2];
  const float* lp1_b1 = (const float*)d_in[3];
  const float* lp1_w2 = (const float*)d_in[4];
  const float* lp1_b2 = (const float*)d_in[5];
  const float* rp1_w1 = (const float*)d_in[6];
  const float* rp1_b1 = (const float*)d_in[7];
  const float* rp1_w2 = (const float*)d_in[8];
  const float* rp1_b2 = (const float*)d_in[9];
  const float* lp2_w1 = (const float*)d_in[10];
  const float* lp2_b1 = (const float*)d_in[11];
  const float* lp2_w2 = (const float*)d_in[12];
  const float* lp2_b2 = (const float*)d_in[13];
  const float* rp2_w1 = (const float*)d_in[14];
  const float* rp2_b1 = (const float*)d_in[15];
  const float* rp2_w2 = (const float*)d_in[16];
  const float* rp2_b2 = (const float*)d_in[17];
  const float* lp3_w  = (const float*)d_in[18];
  const float* lp3_b  = (const float*)d_in[19];
  const float* rp3_w  = (const float*)d_in[20];
  const float* rp3_b  = (const float*)d_in[21];

  short* ws = (short*)d_ws;
  const size_t SZ = (size_t)Bb * Tt * Cc;    // 8.4M bf16 elems
  short* HF  = ws;                           // H (phase 1) / F (phase 2), 8.4M
  short* Ql  = ws + SZ;
  short* Qr  = ws + 2 * SZ;
  short* VTl = ws + 3 * SZ;
  short* VTr = ws + 4 * SZ;
  short* Sb  = ws + 5 * SZ;                  // 4 batches of scores: 16.78M elems
  // total: 7*SZ = 58.7M elems = 117.4 MB

  float* out_l = (float*)d_out;
  float* out_r = (float*)d_out + SZ;

  const float scale = 0.04419417382415922f;  // 512^-0.5
  const int MT = Bb * Tt;                    // 16384
  const long long sQ = (long long)Tt * Cc;   // 1,048,576
  const long long sS = (long long)Tt * Tt;   // 4,194,304

  dim3 blk(256);
  dim3 gProj(Cc / 128, MT / 128, 1);         // 4 x 128
  dim3 gScore(Tt / 128, Tt / 128, 4);        // 16 x 16 x 4 (half the batches)
  dim3 gPV(Cc / 128, Tt / 128, 4);           // 4 x 16 x 4
  const int gDW = Bb * Tt * Cc / 8 / 256;
  dim3 gDWT(Tt / 32, Cc / 64, Bb);

  // ---- phase 1: pointwise conv (GEMM+bias) -> depthwise conv, H reused ----
  gemm_bt<0><<<gProj, blk, 0, stream>>>(x_l, lp1_w1, HF, lp1_b1, nullptr, MT, Cc, Cc, 0, 0, 0, 1.f);
  dw_kernel <<<gDW, blk, 0, stream>>>(HF, lp1_w2, lp1_b2, Ql);
  gemm_bt<0><<<gProj, blk, 0, stream>>>(x_r, rp1_w1, HF, rp1_b1, nullptr, MT, Cc, Cc, 0, 0, 0, 1.f);
  dw_kernel <<<gDW, blk, 0, stream>>>(HF, rp1_w2, rp1_b2, Qr);
  gemm_bt<0><<<gProj, blk, 0, stream>>>(x_l, lp2_w1, HF, lp2_b1, nullptr, MT, Cc, Cc, 0, 0, 0, 1.f);
  dwt_kernel<<<gDWT, blk, 0, stream>>>(HF, lp2_w2, lp2_b2, VTl);
  gemm_bt<0><<<gProj, blk, 0, stream>>>(x_r, rp2_w1, HF, rp2_b1, nullptr, MT, Cc, Cc, 0, 0, 0, 1.f);
  dwt_kernel<<<gDWT, blk, 0, stream>>>(HF, rp2_w2, rp2_b2, VTr);

  // ---- direction A: F_r2l = softmax_rows(Ql Qr^T * scale) @ Vr ----
  for (int g = 0; g < 2; ++g) {
    const long long o = (long long)g * 4 * sQ;
    gemm_bt<1><<<gScore, blk, 0, stream>>>(Ql + o, Qr + o, Sb, nullptr, nullptr, Tt, Tt, Cc, sQ, sQ, sS, scale);
    softmax_kernel<<<4 * Tt, blk, 0, stream>>>(Sb);
    gemm_bt<2><<<gPV, blk, 0, stream>>>(Sb, VTr + o, HF + o, nullptr, nullptr, Tt, Cc, Tt, sS, sQ, sQ, 1.f);
  }
  gemm_bt<3><<<gProj, blk, 0, stream>>>(HF, lp3_w, out_l, lp3_b, x_l, MT, Cc, Cc, 0, 0, 0, 1.f);

  // ---- direction B: F_l2r = softmax_rows(Qr Ql^T * scale) @ Vl ----
  for (int g = 0; g < 2; ++g) {
    const long long o = (long long)g * 4 * sQ;
    gemm_bt<1><<<gScore, blk, 0, stream>>>(Qr + o, Ql + o, Sb, nullptr, nullptr, Tt, Tt, Cc, sQ, sQ, sS, scale);
    softmax_kernel<<<4 * Tt, blk, 0, stream>>>(Sb);
    gemm_bt<2><<<gPV, blk, 0, stream>>>(Sb, VTl + o, HF + o, nullptr, nullptr, Tt, Cc, Tt, sS, sQ, sQ, 1.f);
  }
  gemm_bt<3><<<gProj, blk, 0, stream>>>(HF, rp3_w, out_r, rp3_b, x_r, MT, Cc, Cc, 0, 0, 0, 1.f);

  (void)in_sizes; (void)n_in; (void)out_size; (void)ws_size;
}

// Round 3
// 545.973 us; speedup vs baseline: 1.2527x; 1.2527x over previous
//
#include <hip/hip_runtime.h>
#include <stdint.h>

#define Bb 8
#define Tt 2048
#define Cc 512

typedef __attribute__((ext_vector_type(8))) short short8;
typedef __attribute__((ext_vector_type(4))) float f32x4;

__device__ __forceinline__ float b2f(short s) {
  unsigned int x = ((unsigned int)(unsigned short)s) << 16;
  return __builtin_bit_cast(float, x);
}
__device__ __forceinline__ short f2b(float f) {
  unsigned int x = __builtin_bit_cast(unsigned int, f);
  x += 0x7fffu + ((x >> 16) & 1u);   // round-to-nearest-even
  return (short)(x >> 16);
}

// ---------------------------------------------------------------------------
// GEMM: C[m,n] = epilogue( sum_k A[m,k] * B[n,k] )   (B row-major N x K, bf16)
// MODE 0: A fp32,                    C bf16, +bias[n]            (pointwise)
// MODE 1: A bf16,                    C bf16, *scale              (scores)
// MODE 2: A bf16 + exp(a-mx)*inv,    C bf16                      (softmax@V)
// MODE 3: A bf16,                    C fp32, +bias[n]+resid[m,n] (out proj)
// 128x128 tile, BK=64, 4 waves 2x2, wave tile 64x64 via 4x4 MFMA 16x16x32.
// LDS: 16B chunk (m,kc) at ((kc*128+(m^kc))*8): coalesced + conflict-free b128.
// ---------------------------------------------------------------------------
template<int MODE>
__global__ __launch_bounds__(256, 2)
void gemm_bt(const void* __restrict__ Av, const void* __restrict__ Bv,
             void* __restrict__ Cv, const float* __restrict__ bias,
             const float* __restrict__ resid, const float2* __restrict__ stats,
             int M, int N, int K,
             long long sA, long long sB, long long sC, float scale)
{
  __shared__ __align__(16) short ldsA[8 * 128 * 8];
  __shared__ __align__(16) short ldsB[8 * 128 * 8];
  const int tid  = threadIdx.x;
  const int lane = tid & 63;
  const int bm = blockIdx.y * 128;
  const int bn = blockIdx.x * 128;
  const long long zoA = (long long)blockIdx.z * sA;
  const long long zoB = (long long)blockIdx.z * sB;
  const long long zoC = (long long)blockIdx.z * sC;
  const int wv = tid >> 6;
  const int wm = (wv >> 1) << 6;
  const int wn = (wv & 1) << 6;

  f32x4 zero4 = {0.f, 0.f, 0.f, 0.f};
  f32x4 acc[4][4];
#pragma unroll
  for (int i = 0; i < 4; ++i)
#pragma unroll
    for (int j = 0; j < 4; ++j)
      acc[i][j] = zero4;

  const int sm  = tid >> 3;  // 0..31
  const int skc = tid & 7;   // 0..7 (k-chunk of 8 elems)

  float2 stw[4];
  if constexpr (MODE == 2) {
#pragma unroll
    for (int r = 0; r < 4; ++r)
      stw[r] = stats[(size_t)blockIdx.z * M + bm + r * 32 + sm];
  }

  for (int k0 = 0; k0 < K; k0 += 64) {
#pragma unroll
    for (int r = 0; r < 4; ++r) {
      const int m = r * 32 + sm;
      short8 av, bv;
      if constexpr (MODE == 0) {
        const float* ap = (const float*)Av + zoA + (size_t)(bm + m) * K + k0 + skc * 8;
        float4 f0 = *(const float4*)ap;
        float4 f1 = *(const float4*)(ap + 4);
        av[0] = f2b(f0.x); av[1] = f2b(f0.y); av[2] = f2b(f0.z); av[3] = f2b(f0.w);
        av[4] = f2b(f1.x); av[5] = f2b(f1.y); av[6] = f2b(f1.z); av[7] = f2b(f1.w);
      } else if constexpr (MODE == 2) {
        short8 sv = *(const short8*)((const short*)Av + zoA + (size_t)(bm + m) * K + k0 + skc * 8);
#pragma unroll
        for (int j = 0; j < 8; ++j)
          av[j] = f2b(__expf(b2f(sv[j]) - stw[r].x) * stw[r].y);
      } else {
        av = *(const short8*)((const short*)Av + zoA + (size_t)(bm + m) * K + k0 + skc * 8);
      }
      bv = *(const short8*)((const short*)Bv + zoB + (size_t)(bn + m) * K + k0 + skc * 8);
      const int di = ((skc << 7) + (m ^ skc)) << 3;
      *(short8*)&ldsA[di] = av;
      *(short8*)&ldsB[di] = bv;
    }
    __syncthreads();
#pragma unroll
    for (int kk = 0; kk < 2; ++kk) {
      const int kcr = (kk << 2) + (lane >> 4);
      short8 af[4], bfv[4];
#pragma unroll
      for (int i = 0; i < 4; ++i) {
        const int ma = wm + i * 16 + (lane & 15);
        const int nb = wn + i * 16 + (lane & 15);
        af[i]  = *(const short8*)&ldsA[((kcr << 7) + (ma ^ kcr)) << 3];
        bfv[i] = *(const short8*)&ldsB[((kcr << 7) + (nb ^ kcr)) << 3];
      }
#pragma unroll
      for (int i = 0; i < 4; ++i)
#pragma unroll
        for (int j = 0; j < 4; ++j)
          acc[i][j] = __builtin_amdgcn_mfma_f32_16x16x32_bf16(af[i], bfv[j], acc[i][j], 0, 0, 0);
    }
    __syncthreads();
  }

  // C/D layout: col = lane&15, row = (lane>>4)*4 + reg  [measured m89/m91]
#pragma unroll
  for (int i = 0; i < 4; ++i) {
    const int row0 = bm + wm + i * 16 + ((lane >> 4) << 2);
#pragma unroll
    for (int j = 0; j < 4; ++j) {
      const int n = bn + wn + j * 16 + (lane & 15);
      float badd = 0.f;
      if (MODE == 0 || MODE == 3) badd = bias[n];
#pragma unroll
      for (int r = 0; r < 4; ++r) {
        float val = acc[i][j][r];
        if (MODE == 1) val *= scale;
        if (MODE == 0) val += badd;
        if constexpr (MODE == 3) {
          val += badd + resid[zoC + (size_t)(row0 + r) * N + n];
          ((float*)Cv)[zoC + (size_t)(row0 + r) * N + n] = val;
        } else {
          ((short*)Cv)[zoC + (size_t)(row0 + r) * N + n] = f2b(val);
        }
      }
    }
  }
}

// ---------------------------------------------------------------------------
// One-shot weight/bias packing: fp32 -> bf16, proj pairs concatenated to N=1024.
// Wl=[lp1_w1;lp2_w1], Wr=[rp1_w1;rp2_w1], W3l, W3r, BL=[lp1_b1;lp2_b1], BR.
// ---------------------------------------------------------------------------
__global__ __launch_bounds__(256)
void pack_all(const float* __restrict__ lw1a, const float* __restrict__ lw1b,
              const float* __restrict__ rw1a, const float* __restrict__ rw1b,
              const float* __restrict__ w3lf, const float* __restrict__ w3rf,
              const float* __restrict__ lb1a, const float* __restrict__ lb1b,
              const float* __restrict__ rb1a, const float* __restrict__ rb1b,
              short* __restrict__ Wl, short* __restrict__ Wr,
              short* __restrict__ W3l, short* __restrict__ W3r,
              float* __restrict__ BL, float* __restrict__ BR)
{
  const int i = blockIdx.x * 256 + threadIdx.x;
  if (i < 524288) {
    Wl[i] = f2b(i < 262144 ? lw1a[i] : lw1b[i - 262144]);
  } else if (i < 1048576) {
    const int j = i - 524288;
    Wr[j] = f2b(j < 262144 ? rw1a[j] : rw1b[j - 262144]);
  } else if (i < 1310720) {
    W3l[i - 1048576] = f2b(w3lf[i - 1048576]);
  } else if (i < 1572864) {
    W3r[i - 1310720] = f2b(w3rf[i - 1310720]);
  } else if (i < 1573888) {
    const int j = i - 1572864;
    BL[j] = j < 512 ? lb1a[j] : lb1b[j - 512];
  } else if (i < 1574912) {
    const int j = i - 1573888;
    BR[j] = j < 512 ? rb1a[j] : rb1b[j - 512];
  }
}

// ---------------------------------------------------------------------------
// Depthwise conv k=3 pad=1 over T. H has row stride 1024 (fused proj output),
// column slice [colOff, colOff+512). Output (B,T,512) bf16.
// ---------------------------------------------------------------------------
__global__ __launch_bounds__(256)
void dw_kernel(const short* __restrict__ H, const float* __restrict__ w2,
               const float* __restrict__ b2, short* __restrict__ out, int colOff)
{
  const int idx = blockIdx.x * 256 + threadIdx.x;   // over B*T*512/8
  const int c8 = idx & 63;
  const int bt = idx >> 6;
  const int t  = bt & (Tt - 1);
  const int c  = c8 << 3;
  const short* base = H + (size_t)bt * 1024 + colOff + c;
  short8 zz = {0, 0, 0, 0, 0, 0, 0, 0};
  short8 hm = zz, hp = zz;
  short8 h0 = *(const short8*)base;
  if (t > 0)      hm = *(const short8*)(base - 1024);
  if (t < Tt - 1) hp = *(const short8*)(base + 1024);
  short8 o;
#pragma unroll
  for (int j = 0; j < 8; ++j) {
    const int cj = c + j;
    float val = b2f(hm[j]) * w2[cj * 3 + 0]
              + b2f(h0[j]) * w2[cj * 3 + 1]
              + b2f(hp[j]) * w2[cj * 3 + 2]
              + b2[cj];
    o[j] = f2b(val);
  }
  *(short8*)(out + (size_t)bt * Cc + c) = o;
}

// ---------------------------------------------------------------------------
// Depthwise conv + transpose: outT[b,c,t] (bf16). H row stride 1024, slice at
// colOff. grid (T/32, 512/64, B), block 256.
// ---------------------------------------------------------------------------
__global__ __launch_bounds__(256)
void dwt_kernel(const short* __restrict__ H, const float* __restrict__ w2,
                const float* __restrict__ b2, short* __restrict__ outT, int colOff)
{
  const int b  = blockIdx.z;
  const int c  = blockIdx.y * 64 + (threadIdx.x & 63);
  const int tb = blockIdx.x * 32 + (threadIdx.x >> 6) * 8;
  const short* base = H + ((size_t)b * Tt) * 1024 + colOff + c;
  float h[10];
#pragma unroll
  for (int i = 0; i < 10; ++i) {
    const int t = tb - 1 + i;
    h[i] = (t >= 0 && t < Tt) ? b2f(base[(size_t)t * 1024]) : 0.f;
  }
  const float w0 = w2[c * 3 + 0];
  const float w1 = w2[c * 3 + 1];
  const float wp = w2[c * 3 + 2];
  const float bb = b2[c];
  short8 o;
#pragma unroll
  for (int j = 0; j < 8; ++j)
    o[j] = f2b(h[j] * w0 + h[j + 1] * w1 + h[j + 2] * wp + bb);
  *(short8*)(outT + ((size_t)b * Cc + c) * Tt + tb) = o;
}

// ---------------------------------------------------------------------------
// Row stats: per row of S (length 2048, bf16) write {max, 1/sum(exp(x-max))}.
// One block per row.
// ---------------------------------------------------------------------------
__global__ __launch_bounds__(256)
void stats_kernel(const short* __restrict__ S, float2* __restrict__ st)
{
  __shared__ float red[4];
  const size_t row = blockIdx.x;
  const short8 v = *((const short8*)(S + row * (size_t)Tt) + threadIdx.x);
  float x[8];
  float mx = -1e30f;
#pragma unroll
  for (int j = 0; j < 8; ++j) { x[j] = b2f(v[j]); mx = fmaxf(mx, x[j]); }
#pragma unroll
  for (int off = 32; off > 0; off >>= 1) mx = fmaxf(mx, __shfl_xor(mx, off, 64));
  const int wvi = threadIdx.x >> 6;
  if ((threadIdx.x & 63) == 0) red[wvi] = mx;
  __syncthreads();
  mx = fmaxf(fmaxf(red[0], red[1]), fmaxf(red[2], red[3]));
  __syncthreads();
  float s = 0.f;
#pragma unroll
  for (int j = 0; j < 8; ++j) s += __expf(x[j] - mx);
#pragma unroll
  for (int off = 32; off > 0; off >>= 1) s += __shfl_xor(s, off, 64);
  if ((threadIdx.x & 63) == 0) red[wvi] = s;
  __syncthreads();
  if (threadIdx.x == 0) {
    float2 o; o.x = mx; o.y = 1.f / (red[0] + red[1] + red[2] + red[3]);
    st[row] = o;
  }
}

// ---------------------------------------------------------------------------
extern "C" void kernel_launch(void* const* d_in, const int* in_sizes, int n_in,
                              void* d_out, int out_size, void* d_ws, size_t ws_size,
                              hipStream_t stream)
{
  const float* x_l    = (const float*)d_in[0];
  const float* x_r    = (const float*)d_in[1];
  const float* lp1_w1 = (const float*)d_in[2];
  const float* lp1_b1 = (const float*)d_in[3];
  const float* lp1_w2 = (const float*)d_in[4];
  const float* lp1_b2 = (const float*)d_in[5];
  const float* rp1_w1 = (const float*)d_in[6];
  const float* rp1_b1 = (const float*)d_in[7];
  const float* rp1_w2 = (const float*)d_in[8];
  const float* rp1_b2 = (const float*)d_in[9];
  const float* lp2_w1 = (const float*)d_in[10];
  const float* lp2_b1 = (const float*)d_in[11];
  const float* lp2_w2 = (const float*)d_in[12];
  const float* lp2_b2 = (const float*)d_in[13];
  const float* rp2_w1 = (const float*)d_in[14];
  const float* rp2_b1 = (const float*)d_in[15];
  const float* rp2_w2 = (const float*)d_in[16];
  const float* rp2_b2 = (const float*)d_in[17];
  const float* lp3_w  = (const float*)d_in[18];
  const float* lp3_b  = (const float*)d_in[19];
  const float* rp3_w  = (const float*)d_in[20];
  const float* rp3_b  = (const float*)d_in[21];

  short* ws = (short*)d_ws;
  const size_t SZ = (size_t)Bb * Tt * Cc;    // 8,388,608 bf16 elems (16.78 MB)
  short* Ql  = ws;
  short* Qr  = ws + SZ;
  short* VTl = ws + 2 * SZ;
  short* VTr = ws + 3 * SZ;
  short* Fb  = ws + 4 * SZ;
  short* Sb  = ws + 5 * SZ;                  // scores; plan A 4*SZ, plan B 2*SZ
  short* H   = Sb;                           // fused proj out (2*SZ), phase 1 only

  const size_t W_PAIR = 524288, W_SING = 262144;
  const size_t tail_elems = 2 * W_PAIR + 2 * W_SING + 2 * 2048 + 65536;
  const bool planA = ws_size >= 2 * (9 * SZ + tail_elems);   // ~154.3 MB
  const size_t tail = planA ? 9 * SZ : 7 * SZ;
  short* Wl  = ws + tail;
  short* Wr  = Wl + W_PAIR;
  short* W3l = Wr + W_PAIR;
  short* W3r = W3l + W_SING;
  float* BL  = (float*)(W3r + W_SING);
  float* BR  = BL + 1024;
  float2* stats = (float2*)(BR + 1024);

  float* out_l = (float*)d_out;
  float* out_r = (float*)d_out + SZ;

  const float scale = 0.04419417382415922f;  // 512^-0.5
  const int MT = Bb * Tt;                    // 16384
  const long long sQ = (long long)Tt * Cc;
  const long long sS = (long long)Tt * Tt;
  const int nz = planA ? 8 : 4;
  const int ng = planA ? 1 : 2;

  dim3 blk(256);

  // ---- phase 0: pack weights ----
  pack_all<<<6152, blk, 0, stream>>>(lp1_w1, lp2_w1, rp1_w1, rp2_w1, lp3_w, rp3_w,
                                     lp1_b1, lp2_b1, rp1_b1, rp2_b1,
                                     Wl, Wr, W3l, W3r, BL, BR);

  // ---- phase 1: fused pointwise proj (N=1024) -> depthwise convs ----
  gemm_bt<0><<<dim3(8, 128, 1), blk, 0, stream>>>(x_l, Wl, H, BL, nullptr, nullptr,
                                                  MT, 1024, Cc, 0, 0, 0, 1.f);
  dw_kernel <<<4096, blk, 0, stream>>>(H, lp1_w2, lp1_b2, Ql, 0);
  dwt_kernel<<<dim3(Tt / 32, 8, Bb), blk, 0, stream>>>(H, lp2_w2, lp2_b2, VTl, 512);

  gemm_bt<0><<<dim3(8, 128, 1), blk, 0, stream>>>(x_r, Wr, H, BR, nullptr, nullptr,
                                                  MT, 1024, Cc, 0, 0, 0, 1.f);
  dw_kernel <<<4096, blk, 0, stream>>>(H, rp1_w2, rp1_b2, Qr, 0);
  dwt_kernel<<<dim3(Tt / 32, 8, Bb), blk, 0, stream>>>(H, rp2_w2, rp2_b2, VTr, 512);

  // ---- phase 2: attention, both directions ----
  for (int dir = 0; dir < 2; ++dir) {
    const short* Qa = dir == 0 ? Ql : Qr;
    const short* Qb = dir == 0 ? Qr : Ql;
    const short* Vt = dir == 0 ? VTr : VTl;
    const short* W3 = dir == 0 ? W3l : W3r;
    const float* b3 = dir == 0 ? lp3_b : rp3_b;
    const float* xr = dir == 0 ? x_l : x_r;
    float* outp     = dir == 0 ? out_l : out_r;

    for (int g = 0; g < ng; ++g) {
      const long long o = (long long)g * nz * sQ;
      gemm_bt<1><<<dim3(Tt / 128, Tt / 128, nz), blk, 0, stream>>>(
          Qa + o, Qb + o, Sb, nullptr, nullptr, nullptr, Tt, Tt, Cc, sQ, sQ, sS, scale);
      stats_kernel<<<nz * Tt, blk, 0, stream>>>(Sb, stats);
      gemm_bt<2><<<dim3(Cc / 128, Tt / 128, nz), blk, 0, stream>>>(
          Sb, Vt + o, Fb + o, nullptr, nullptr, stats, Tt, Cc, Tt, sS, sQ, sQ, 1.f);
    }
    gemm_bt<3><<<dim3(Cc / 128, MT / 128, 1), blk, 0, stream>>>(
        Fb, W3, outp, b3, xr, nullptr, MT, Cc, Cc, 0, 0, 0, 1.f);
  }

  (void)in_sizes; (void)n_in; (void)out_size;
}